// Round 1
// baseline (323.075 us; speedup 1.0000x reference)
//
#include <hip/hip_runtime.h>

#define S_LEN 4096
#define NHEADS 16
#define HD 64
#define HDIM 1024

typedef __attribute__((ext_vector_type(8))) __bf16 bf16x8;
typedef __attribute__((ext_vector_type(4))) float f32x4;
typedef unsigned short u16;

static __device__ __forceinline__ u16 f2bu(float f) {
    unsigned u = __builtin_bit_cast(unsigned, f);
    u += 0x7FFFu + ((u >> 16) & 1u);
    return (u16)(u >> 16);
}

// swizzled LDS fragment read: tile rows are 128B, XOR-swizzle bit pattern ((row&7)<<4)
static __device__ __forceinline__ bf16x8 read_frag(const u16* lds, int row, int kbyte) {
    int c = kbyte ^ ((row & 7) << 4);
    return *reinterpret_cast<const bf16x8*>(reinterpret_cast<const char*>(lds) + row * 128 + c);
}

static __device__ __forceinline__ void stage_gll(const u16* __restrict__ src, u16* lds, unsigned ldsbyte) {
    __builtin_amdgcn_global_load_lds(
        (const __attribute__((address_space(1))) void*)src,
        (__attribute__((address_space(3))) void*)(reinterpret_cast<char*>(lds) + ldsbyte),
        16, 0, 0);
}

__global__ void cvt_f32_bf16(const float* __restrict__ src, u16* __restrict__ dst, int n4) {
    int i = blockIdx.x * blockDim.x + threadIdx.x;
    if (i < n4) {
        float4 v = reinterpret_cast<const float4*>(src)[i];
        ushort4 o;
        o.x = f2bu(v.x); o.y = f2bu(v.y); o.z = f2bu(v.z); o.w = f2bu(v.w);
        reinterpret_cast<ushort4*>(dst)[i] = o;
    }
}

// C[M,N] = A[M,K] @ W[N,K]^T,  M=4096 N=1024 K=1024, bf16 in, epilogue by mode:
// mode 0: fp32 out [s][1024]
// mode 1: RoPE + 0.125 scale, bf16 out [h][s][64]   (Q)
// mode 2: RoPE, bf16 out [h][s][64]                 (K)
// mode 3: bf16 out transposed [h][d][s]             (V^T)
__global__ __launch_bounds__(256) void gemm_bt(
    const u16* __restrict__ A, const u16* __restrict__ W,
    float* __restrict__ outF, u16* __restrict__ outB,
    const float* __restrict__ cosT, const float* __restrict__ sinT,
    int mode)
{
    __shared__ u16 At[128 * 64];
    __shared__ u16 Bt[128 * 64];
    const int tid = threadIdx.x;
    const int wid = tid >> 6, lane = tid & 63;
    const int wm = wid >> 1, wn = wid & 1;
    const int lj = lane >> 4, lc = lane & 15;
    const int m0 = blockIdx.y * 128, n0 = blockIdx.x * 128;

    f32x4 acc[4][4];
#pragma unroll
    for (int i = 0; i < 4; ++i)
#pragma unroll
        for (int j = 0; j < 4; ++j) acc[i][j] = 0.0f;

    for (int k0 = 0; k0 < HDIM; k0 += 64) {
        __syncthreads();
#pragma unroll
        for (int r = 0; r < 4; ++r) {
            int idx = (r << 8) + tid;
            int row = idx >> 3;              // 8 x 16B chunks per 128B row
            int c = (idx & 7) << 4;
            int csw = c ^ ((row & 7) << 4);  // inverse-swizzled source (same involution)
            unsigned lb = (unsigned)(idx & ~63) << 4;  // wave-uniform LDS base
            stage_gll(A + (size_t)(m0 + row) * HDIM + k0 + (csw >> 1), At, lb);
            stage_gll(W + (size_t)(n0 + row) * HDIM + k0 + (csw >> 1), Bt, lb);
        }
        __syncthreads();
#pragma unroll
        for (int kb = 0; kb < 2; ++kb) {
            int kbyte = (kb << 6) + (lj << 4);
            bf16x8 af[4], bfr[4];
#pragma unroll
            for (int mf = 0; mf < 4; ++mf) af[mf] = read_frag(At, (wm << 6) + (mf << 4) + lc, kbyte);
#pragma unroll
            for (int nf = 0; nf < 4; ++nf) bfr[nf] = read_frag(Bt, (wn << 6) + (nf << 4) + lc, kbyte);
#pragma unroll
            for (int mf = 0; mf < 4; ++mf)
#pragma unroll
                for (int nf = 0; nf < 4; ++nf)
                    acc[mf][nf] = __builtin_amdgcn_mfma_f32_16x16x32_bf16(af[mf], bfr[nf], acc[mf][nf], 0, 0, 0);
        }
    }

    const int mrow0 = m0 + (wm << 6);
    const int ncol0 = n0 + (wn << 6);
    if (mode == 0) {
#pragma unroll
        for (int mf = 0; mf < 4; ++mf)
#pragma unroll
            for (int nf = 0; nf < 4; ++nf)
#pragma unroll
                for (int j = 0; j < 4; ++j) {
                    int s = mrow0 + (mf << 4) + (lj << 2) + j;
                    int o = ncol0 + (nf << 4) + lc;
                    outF[(size_t)s * HDIM + o] = acc[mf][nf][j];
                }
    } else if (mode == 3) {
#pragma unroll
        for (int mf = 0; mf < 4; ++mf)
#pragma unroll
            for (int nf = 0; nf < 4; ++nf)
#pragma unroll
                for (int j = 0; j < 4; ++j) {
                    int s = mrow0 + (mf << 4) + (lj << 2) + j;
                    int o = ncol0 + (nf << 4) + lc;
                    outB[((size_t)(o >> 6) * HD + (o & 63)) * S_LEN + s] = f2bu(acc[mf][nf][j]);
                }
    } else {
        const float sc = (mode == 1) ? 0.125f : 1.0f;
#pragma unroll
        for (int mf = 0; mf < 4; ++mf) {
            float nv[4][4];
#pragma unroll
            for (int nf = 0; nf < 4; ++nf)
#pragma unroll
                for (int j = 0; j < 4; ++j) {
                    int s = mrow0 + (mf << 4) + (lj << 2) + j;
                    int o = ncol0 + (nf << 4) + lc;
                    int d = o & 63;
                    float x  = acc[mf][nf][j];
                    float xp = acc[mf][nf ^ 2][j];   // partner d +/- 32 lives 2 n-frags away
                    float cv = cosT[(size_t)s * HD + d];
                    float sv = sinT[(size_t)s * HD + d];
                    float rot = (d < 32) ? -xp : xp;
                    nv[nf][j] = (x * cv + rot * sv) * sc;
                }
#pragma unroll
            for (int nf = 0; nf < 4; ++nf)
#pragma unroll
                for (int j = 0; j < 4; ++j) {
                    int s = mrow0 + (mf << 4) + (lj << 2) + j;
                    int o = ncol0 + (nf << 4) + lc;
                    outB[((size_t)(o >> 6) * S_LEN + s) * HD + (o & 63)] = f2bu(nv[nf][j]);
                }
        }
    }
}

// Flash attention, causal. Q,K: [h][s][64] bf16 (Q pre-scaled by 1/8, both roped).
// VT: [h][d][s] bf16. Out: attn_out [s][h*64+d] bf16.
__global__ __launch_bounds__(256) void attn_fwd(
    const u16* __restrict__ Q, const u16* __restrict__ K,
    const u16* __restrict__ VT, u16* __restrict__ AO)
{
    __shared__ u16 Kt[64 * 64];      // [kv][d], swizzled
    __shared__ u16 Vt[64 * 64];      // [d][kv], swizzled
    __shared__ u16 Pt[4][32 * 64];   // per-wave P, swizzled

    const int tid = threadIdx.x;
    const int wid = tid >> 6, lane = tid & 63;
    const int lj = lane >> 4, lc = lane & 15;
    const int h = blockIdx.y, qt = blockIdx.x;
    const int qbase = qt * 128 + wid * 32;     // this wave's global q-row base (32 rows)

    const u16* Qh  = Q  + (size_t)h * S_LEN * HD;
    const u16* Kh  = K  + (size_t)h * S_LEN * HD;
    const u16* VTh = VT + (size_t)h * HD * S_LEN;
    u16* Pw = Pt[wid];

    bf16x8 qA[2][2];
#pragma unroll
    for (int qf = 0; qf < 2; ++qf)
#pragma unroll
        for (int kb = 0; kb < 2; ++kb)
            qA[qf][kb] = *reinterpret_cast<const bf16x8*>(
                Qh + (size_t)(qbase + (qf << 4) + lc) * HD + (kb << 5) + (lj << 3));

    f32x4 accO[2][4];
    float m_run[2][4], l_run[2][4];
#pragma unroll
    for (int qf = 0; qf < 2; ++qf) {
#pragma unroll
        for (int df = 0; df < 4; ++df) accO[qf][df] = 0.0f;
#pragma unroll
        for (int j = 0; j < 4; ++j) { m_run[qf][j] = -1e30f; l_run[qf][j] = 0.0f; }
    }

    const int nt = qt * 2 + 2;   // causal: kv tiles needed
    for (int t = 0; t < nt; ++t) {
        const int kv0 = t * 64;
        __syncthreads();
#pragma unroll
        for (int r = 0; r < 2; ++r) {
            int idx = (r << 8) + tid;
            int row = idx >> 3;
            int c = (idx & 7) << 4;
            int csw = c ^ ((row & 7) << 4);
            unsigned lb = (unsigned)(idx & ~63) << 4;
            stage_gll(Kh + (size_t)(kv0 + row) * HD + (csw >> 1), Kt, lb);
            stage_gll(VTh + (size_t)row * S_LEN + kv0 + (csw >> 1), Vt, lb);
        }
        __syncthreads();

        const bool active = (kv0 <= qbase + 31);
        if (active) {
            const bool needmask = (kv0 + 63 > qbase);
            f32x4 sf[2][4];
#pragma unroll
            for (int qf = 0; qf < 2; ++qf)
#pragma unroll
                for (int nf = 0; nf < 4; ++nf) sf[qf][nf] = 0.0f;
#pragma unroll
            for (int kb = 0; kb < 2; ++kb) {
                int kbyte = (kb << 6) + (lj << 4);
                bf16x8 kf[4];
#pragma unroll
                for (int nf = 0; nf < 4; ++nf) kf[nf] = read_frag(Kt, (nf << 4) + lc, kbyte);
#pragma unroll
                for (int qf = 0; qf < 2; ++qf)
#pragma unroll
                    for (int nf = 0; nf < 4; ++nf)
                        sf[qf][nf] = __builtin_amdgcn_mfma_f32_16x16x32_bf16(qA[qf][kb], kf[nf], sf[qf][nf], 0, 0, 0);
            }
            if (needmask) {
#pragma unroll
                for (int qf = 0; qf < 2; ++qf)
#pragma unroll
                    for (int nf = 0; nf < 4; ++nf)
#pragma unroll
                        for (int j = 0; j < 4; ++j) {
                            int kvg = kv0 + (nf << 4) + lc;
                            int qg  = qbase + (qf << 4) + (lj << 2) + j;
                            if (kvg > qg) sf[qf][nf][j] = -1e30f;
                        }
            }
#pragma unroll
            for (int qf = 0; qf < 2; ++qf) {
                float mx[4], rs[4];
#pragma unroll
                for (int j = 0; j < 4; ++j)
                    mx[j] = fmaxf(fmaxf(sf[qf][0][j], sf[qf][1][j]), fmaxf(sf[qf][2][j], sf[qf][3][j]));
#pragma unroll
                for (int off = 1; off < 16; off <<= 1)
#pragma unroll
                    for (int j = 0; j < 4; ++j) mx[j] = fmaxf(mx[j], __shfl_xor(mx[j], off));
#pragma unroll
                for (int j = 0; j < 4; ++j) {
                    float mn = fmaxf(m_run[qf][j], mx[j]);
                    float scl = __expf(m_run[qf][j] - mn);
                    m_run[qf][j] = mn;
                    l_run[qf][j] *= scl;
#pragma unroll
                    for (int df = 0; df < 4; ++df) accO[qf][df][j] *= scl;
                    rs[j] = 0.0f;
                }
#pragma unroll
                for (int nf = 0; nf < 4; ++nf)
#pragma unroll
                    for (int j = 0; j < 4; ++j) {
                        float p = __expf(sf[qf][nf][j] - m_run[qf][j]);
                        rs[j] += p;
                        int prow = (qf << 4) + (lj << 2) + j;
                        int cb = (((nf << 4) + lc) << 1) ^ ((prow & 7) << 4);
                        Pw[prow * 64 + (cb >> 1)] = f2bu(p);
                    }
#pragma unroll
                for (int off = 1; off < 16; off <<= 1)
#pragma unroll
                    for (int j = 0; j < 4; ++j) rs[j] += __shfl_xor(rs[j], off);
#pragma unroll
                for (int j = 0; j < 4; ++j) l_run[qf][j] += rs[j];
            }
            // PV
#pragma unroll
            for (int kb = 0; kb < 2; ++kb) {
                int kbyte = (kb << 6) + (lj << 4);
                bf16x8 vf[4];
#pragma unroll
                for (int df = 0; df < 4; ++df) vf[df] = read_frag(Vt, (df << 4) + lc, kbyte);
#pragma unroll
                for (int qf = 0; qf < 2; ++qf) {
                    bf16x8 pf = read_frag(Pw, (qf << 4) + lc, kbyte);
#pragma unroll
                    for (int df = 0; df < 4; ++df)
                        accO[qf][df] = __builtin_amdgcn_mfma_f32_16x16x32_bf16(pf, vf[df], accO[qf][df], 0, 0, 0);
                }
            }
        }
    }

#pragma unroll
    for (int qf = 0; qf < 2; ++qf)
#pragma unroll
        for (int df = 0; df < 4; ++df)
#pragma unroll
            for (int j = 0; j < 4; ++j) {
                int s = qbase + (qf << 4) + (lj << 2) + j;
                int d = (df << 4) + lc;
                float v = accO[qf][df][j] / l_run[qf][j];
                AO[(size_t)s * HDIM + h * HD + d] = f2bu(v);
            }
}

extern "C" void kernel_launch(void* const* d_in, const int* in_sizes, int n_in,
                              void* d_out, int out_size, void* d_ws, size_t ws_size,
                              hipStream_t stream) {
    const float* hidden = (const float*)d_in[0];
    const float* cosT   = (const float*)d_in[1];
    const float* sinT   = (const float*)d_in[2];
    // d_in[3] = attention_mask (fixed causal tril) — implemented directly
    const float* Wq = (const float*)d_in[4];
    const float* Wk = (const float*)d_in[5];
    const float* Wv = (const float*)d_in[6];
    const float* Wo = (const float*)d_in[7];
    float* out = (float*)d_out;

    char* ws = (char*)d_ws;
    u16* Xb  = (u16*)(ws);                       // 8 MB   X bf16 [4096][1024]
    u16* Wqb = (u16*)(ws + (size_t)( 8 << 20));  // 2 MB
    u16* Wkb = (u16*)(ws + (size_t)(10 << 20));  // 2 MB
    u16* Wvb = (u16*)(ws + (size_t)(12 << 20));  // 2 MB
    u16* Wob = (u16*)(ws + (size_t)(14 << 20));  // 2 MB
    u16* Qb  = (u16*)(ws + (size_t)(16 << 20));  // 8 MB   [h][s][64]
    u16* Kb  = (u16*)(ws + (size_t)(24 << 20));  // 8 MB   [h][s][64]
    u16* VTb = (u16*)(ws + (size_t)(32 << 20));  // 8 MB   [h][d][s]
    u16* AOb = (u16*)(ws + (size_t)(40 << 20));  // 8 MB   [s][1024]

    const int n4h = (S_LEN * HDIM) / 4;   // 1048576
    const int n4w = (HDIM * HDIM) / 4;    // 262144
    cvt_f32_bf16<<<n4h / 256, 256, 0, stream>>>(hidden, Xb, n4h);
    cvt_f32_bf16<<<n4w / 256, 256, 0, stream>>>(Wq, Wqb, n4w);
    cvt_f32_bf16<<<n4w / 256, 256, 0, stream>>>(Wk, Wkb, n4w);
    cvt_f32_bf16<<<n4w / 256, 256, 0, stream>>>(Wv, Wvb, n4w);
    cvt_f32_bf16<<<n4w / 256, 256, 0, stream>>>(Wo, Wob, n4w);

    dim3 gg(HDIM / 128, S_LEN / 128);  // (8, 32)
    gemm_bt<<<gg, 256, 0, stream>>>(Xb, Wqb, nullptr, Qb, cosT, sinT, 1);
    gemm_bt<<<gg, 256, 0, stream>>>(Xb, Wkb, nullptr, Kb, cosT, sinT, 2);
    gemm_bt<<<gg, 256, 0, stream>>>(Xb, Wvb, nullptr, VTb, nullptr, nullptr, 3);

    attn_fwd<<<dim3(S_LEN / 128, NHEADS), 256, 0, stream>>>(Qb, Kb, VTb, AOb);

    gemm_bt<<<gg, 256, 0, stream>>>(AOb, Wob, out, nullptr, nullptr, nullptr, 0);
}

// Round 2
// 316.084 us; speedup vs baseline: 1.0221x; 1.0221x over previous
//
#include <hip/hip_runtime.h>

#define S_LEN 4096
#define NHEADS 16
#define HD 64
#define HDIM 1024

typedef __attribute__((ext_vector_type(8))) __bf16 bf16x8;
typedef __attribute__((ext_vector_type(4))) float f32x4;
typedef unsigned short u16;

static __device__ __forceinline__ u16 f2bu(float f) {
    unsigned u = __builtin_bit_cast(unsigned, f);
    u += 0x7FFFu + ((u >> 16) & 1u);
    return (u16)(u >> 16);
}
static __device__ __forceinline__ u16 f2bu_trunc(float f) {
    return (u16)(__builtin_bit_cast(unsigned, f) >> 16);
}
static __device__ __forceinline__ float fexp2(float x) {
    return __builtin_amdgcn_exp2f(x);
}

// swizzled LDS fragment read: tile rows are 128B, XOR-swizzle ((row&7)<<4)
static __device__ __forceinline__ bf16x8 read_frag(const u16* lds, int row, int kbyte) {
    int c = kbyte ^ ((row & 7) << 4);
    return *reinterpret_cast<const bf16x8*>(reinterpret_cast<const char*>(lds) + row * 128 + c);
}

static __device__ __forceinline__ void stage_gll(const u16* __restrict__ src, u16* lds, unsigned ldsbyte) {
    __builtin_amdgcn_global_load_lds(
        (const __attribute__((address_space(1))) void*)src,
        (__attribute__((address_space(3))) void*)(reinterpret_cast<char*>(lds) + ldsbyte),
        16, 0, 0);
}

__global__ void cvt_f32_bf16(const float* __restrict__ src, u16* __restrict__ dst, int n4) {
    int i = blockIdx.x * blockDim.x + threadIdx.x;
    if (i < n4) {
        float4 v = reinterpret_cast<const float4*>(src)[i];
        ushort4 o;
        o.x = f2bu(v.x); o.y = f2bu(v.y); o.z = f2bu(v.z); o.w = f2bu(v.w);
        reinterpret_cast<ushort4*>(dst)[i] = o;
    }
}

// C[M,N] = A[M,K] @ W[N,K]^T,  M=4096 N=1024 K=1024, bf16 in, epilogue by mode:
// mode 0: fp32 out [s][1024]
// mode 1: RoPE + (0.125*log2e) scale, bf16 out [h][s][64]   (Q, exp2-domain)
// mode 2: RoPE, bf16 out [h][s][64]                         (K)
// mode 3: bf16 out transposed [h][d][s]                     (V^T)
__global__ __launch_bounds__(256) void gemm_bt(
    const u16* __restrict__ A, const u16* __restrict__ W,
    float* __restrict__ outF, u16* __restrict__ outB,
    const float* __restrict__ cosT, const float* __restrict__ sinT,
    int mode)
{
    __shared__ u16 At[128 * 64];
    __shared__ u16 Bt[128 * 64];
    const int tid = threadIdx.x;
    const int wid = tid >> 6, lane = tid & 63;
    const int wm = wid >> 1, wn = wid & 1;
    const int lj = lane >> 4, lc = lane & 15;
    const int m0 = blockIdx.y * 128, n0 = blockIdx.x * 128;

    f32x4 acc[4][4];
#pragma unroll
    for (int i = 0; i < 4; ++i)
#pragma unroll
        for (int j = 0; j < 4; ++j) acc[i][j] = 0.0f;

    for (int k0 = 0; k0 < HDIM; k0 += 64) {
        __syncthreads();
#pragma unroll
        for (int r = 0; r < 4; ++r) {
            int idx = (r << 8) + tid;
            int row = idx >> 3;              // 8 x 16B chunks per 128B row
            int c = (idx & 7) << 4;
            int csw = c ^ ((row & 7) << 4);  // inverse-swizzled source (same involution)
            unsigned lb = (unsigned)(idx & ~63) << 4;  // wave-uniform LDS base
            stage_gll(A + (size_t)(m0 + row) * HDIM + k0 + (csw >> 1), At, lb);
            stage_gll(W + (size_t)(n0 + row) * HDIM + k0 + (csw >> 1), Bt, lb);
        }
        __syncthreads();
#pragma unroll
        for (int kb = 0; kb < 2; ++kb) {
            int kbyte = (kb << 6) + (lj << 4);
            bf16x8 af[4], bfr[4];
#pragma unroll
            for (int mf = 0; mf < 4; ++mf) af[mf] = read_frag(At, (wm << 6) + (mf << 4) + lc, kbyte);
#pragma unroll
            for (int nf = 0; nf < 4; ++nf) bfr[nf] = read_frag(Bt, (wn << 6) + (nf << 4) + lc, kbyte);
#pragma unroll
            for (int mf = 0; mf < 4; ++mf)
#pragma unroll
                for (int nf = 0; nf < 4; ++nf)
                    acc[mf][nf] = __builtin_amdgcn_mfma_f32_16x16x32_bf16(af[mf], bfr[nf], acc[mf][nf], 0, 0, 0);
        }
    }

    const int mrow0 = m0 + (wm << 6);
    const int ncol0 = n0 + (wn << 6);
    if (mode == 0) {
#pragma unroll
        for (int mf = 0; mf < 4; ++mf)
#pragma unroll
            for (int nf = 0; nf < 4; ++nf)
#pragma unroll
                for (int j = 0; j < 4; ++j) {
                    int s = mrow0 + (mf << 4) + (lj << 2) + j;
                    int o = ncol0 + (nf << 4) + lc;
                    outF[(size_t)s * HDIM + o] = acc[mf][nf][j];
                }
    } else if (mode == 3) {
#pragma unroll
        for (int mf = 0; mf < 4; ++mf)
#pragma unroll
            for (int nf = 0; nf < 4; ++nf)
#pragma unroll
                for (int j = 0; j < 4; ++j) {
                    int s = mrow0 + (mf << 4) + (lj << 2) + j;
                    int o = ncol0 + (nf << 4) + lc;
                    outB[((size_t)(o >> 6) * HD + (o & 63)) * S_LEN + s] = f2bu(acc[mf][nf][j]);
                }
    } else {
        const float sc = (mode == 1) ? 0.18033688011112042f : 1.0f;  // 0.125*log2(e) for Q
#pragma unroll
        for (int mf = 0; mf < 4; ++mf) {
            float nv[4][4];
#pragma unroll
            for (int nf = 0; nf < 4; ++nf)
#pragma unroll
                for (int j = 0; j < 4; ++j) {
                    int s = mrow0 + (mf << 4) + (lj << 2) + j;
                    int o = ncol0 + (nf << 4) + lc;
                    int d = o & 63;
                    float x  = acc[mf][nf][j];
                    float xp = acc[mf][nf ^ 2][j];   // partner d +/- 32 lives 2 n-frags away
                    float cv = cosT[(size_t)s * HD + d];
                    float sv = sinT[(size_t)s * HD + d];
                    float rot = (d < 32) ? -xp : xp;
                    nv[nf][j] = (x * cv + rot * sv) * sc;
                }
#pragma unroll
            for (int nf = 0; nf < 4; ++nf)
#pragma unroll
                for (int j = 0; j < 4; ++j) {
                    int s = mrow0 + (mf << 4) + (lj << 2) + j;
                    int o = ncol0 + (nf << 4) + lc;
                    outB[((size_t)(o >> 6) * S_LEN + s) * HD + (o & 63)] = f2bu(nv[nf][j]);
                }
        }
    }
}

// Flash attention, causal, exp2-domain (Q pre-scaled by 0.125*log2e).
// Q,K: [h][s][64] bf16 (roped). VT: [h][d][s] bf16. Out: attn_out [s][h*64+d] bf16.
// Block = 4 waves x 16 q-rows = 64 q rows. Grid (64, 16), qt reversed for scheduling.
__global__ __launch_bounds__(256) void attn_fwd(
    const u16* __restrict__ Q, const u16* __restrict__ K,
    const u16* __restrict__ VT, u16* __restrict__ AO)
{
    __shared__ u16 Kt[64 * 64];      // [kv][d], swizzled
    __shared__ u16 Vt[64 * 64];      // [d][kv], swizzled
    __shared__ u16 Pt[4][16 * 64];   // per-wave P (16 q rows x 64 kv), swizzled

    const int tid = threadIdx.x;
    const int wid = tid >> 6, lane = tid & 63;
    const int lj = lane >> 4, lc = lane & 15;
    const int h = blockIdx.y;
    const int qt = (int)gridDim.x - 1 - (int)blockIdx.x;  // heavy tiles dispatch first
    const int qbase = qt * 64 + wid * 16;                 // this wave's 16 q-rows

    const u16* Qh  = Q  + (size_t)h * S_LEN * HD;
    const u16* Kh  = K  + (size_t)h * S_LEN * HD;
    const u16* VTh = VT + (size_t)h * HD * S_LEN;
    u16* Pw = Pt[wid];

    bf16x8 qA[2];
#pragma unroll
    for (int kb = 0; kb < 2; ++kb)
        qA[kb] = *reinterpret_cast<const bf16x8*>(
            Qh + (size_t)(qbase + lc) * HD + (kb << 5) + (lj << 3));

    f32x4 accO[4];
    float m_run[4], l_run[4];
#pragma unroll
    for (int df = 0; df < 4; ++df) accO[df] = 0.0f;
#pragma unroll
    for (int j = 0; j < 4; ++j) { m_run[j] = -1e30f; l_run[j] = 0.0f; }

    const int nt = qt + 1;   // causal: kv tiles needed for rows < (qt+1)*64
    for (int t = 0; t < nt; ++t) {
        const int kv0 = t * 64;
        __syncthreads();
#pragma unroll
        for (int r = 0; r < 2; ++r) {
            int idx = (r << 8) + tid;
            int row = idx >> 3;
            int c = (idx & 7) << 4;
            int csw = c ^ ((row & 7) << 4);
            unsigned lb = (unsigned)(idx & ~63) << 4;
            stage_gll(Kh + (size_t)(kv0 + row) * HD + (csw >> 1), Kt, lb);
            stage_gll(VTh + (size_t)row * S_LEN + kv0 + (csw >> 1), Vt, lb);
        }
        __syncthreads();

        // QK^T : 16 q-rows x 64 kv
        f32x4 sf[4];
#pragma unroll
        for (int nf = 0; nf < 4; ++nf) sf[nf] = 0.0f;
#pragma unroll
        for (int kb = 0; kb < 2; ++kb) {
            int kbyte = (kb << 6) + (lj << 4);
#pragma unroll
            for (int nf = 0; nf < 4; ++nf) {
                bf16x8 kf = read_frag(Kt, (nf << 4) + lc, kbyte);
                sf[nf] = __builtin_amdgcn_mfma_f32_16x16x32_bf16(qA[kb], kf, sf[nf], 0, 0, 0);
            }
        }

        if (kv0 + 63 > qbase) {  // diagonal tile: causal mask
#pragma unroll
            for (int nf = 0; nf < 4; ++nf)
#pragma unroll
                for (int j = 0; j < 4; ++j) {
                    int kvg = kv0 + (nf << 4) + lc;
                    int qg  = qbase + (lj << 2) + j;
                    if (kvg > qg) sf[nf][j] = -1e30f;
                }
        }

        // online softmax (exp2 domain), defer-max
        float mx[4];
#pragma unroll
        for (int j = 0; j < 4; ++j)
            mx[j] = fmaxf(fmaxf(sf[0][j], sf[1][j]), fmaxf(sf[2][j], sf[3][j]));
#pragma unroll
        for (int off = 1; off < 16; off <<= 1)
#pragma unroll
            for (int j = 0; j < 4; ++j) mx[j] = fmaxf(mx[j], __shfl_xor(mx[j], off));

        bool grow = false;
#pragma unroll
        for (int j = 0; j < 4; ++j) grow = grow || (mx[j] > m_run[j] + 8.0f);
        if (__any(grow)) {
#pragma unroll
            for (int j = 0; j < 4; ++j) {
                float mn = fmaxf(m_run[j], mx[j]);
                float scl = fexp2(m_run[j] - mn);
                m_run[j] = mn;
                l_run[j] *= scl;
#pragma unroll
                for (int df = 0; df < 4; ++df) accO[df][j] *= scl;
            }
        }

        float rs[4] = {0.f, 0.f, 0.f, 0.f};
#pragma unroll
        for (int nf = 0; nf < 4; ++nf)
#pragma unroll
            for (int j = 0; j < 4; ++j) {
                float p = fexp2(sf[nf][j] - m_run[j]);
                rs[j] += p;
                int prow = (lj << 2) + j;
                int cb = (((nf << 4) + lc) << 1) ^ ((prow & 7) << 4);
                Pw[prow * 64 + (cb >> 1)] = f2bu_trunc(p);
            }
#pragma unroll
        for (int off = 1; off < 16; off <<= 1)
#pragma unroll
            for (int j = 0; j < 4; ++j) rs[j] += __shfl_xor(rs[j], off);
#pragma unroll
        for (int j = 0; j < 4; ++j) l_run[j] += rs[j];

        // PV
#pragma unroll
        for (int kb = 0; kb < 2; ++kb) {
            int kbyte = (kb << 6) + (lj << 4);
            bf16x8 pf = read_frag(Pw, lc, kbyte);
#pragma unroll
            for (int df = 0; df < 4; ++df) {
                bf16x8 vf = read_frag(Vt, (df << 4) + lc, kbyte);
                accO[df] = __builtin_amdgcn_mfma_f32_16x16x32_bf16(pf, vf, accO[df], 0, 0, 0);
            }
        }
    }

#pragma unroll
    for (int df = 0; df < 4; ++df)
#pragma unroll
        for (int j = 0; j < 4; ++j) {
            int s = qbase + (lj << 2) + j;
            int d = (df << 4) + lc;
            float v = accO[df][j] / l_run[j];
            AO[(size_t)s * HDIM + h * HD + d] = f2bu(v);
        }
}

extern "C" void kernel_launch(void* const* d_in, const int* in_sizes, int n_in,
                              void* d_out, int out_size, void* d_ws, size_t ws_size,
                              hipStream_t stream) {
    const float* hidden = (const float*)d_in[0];
    const float* cosT   = (const float*)d_in[1];
    const float* sinT   = (const float*)d_in[2];
    // d_in[3] = attention_mask (fixed causal tril) — implemented directly
    const float* Wq = (const float*)d_in[4];
    const float* Wk = (const float*)d_in[5];
    const float* Wv = (const float*)d_in[6];
    const float* Wo = (const float*)d_in[7];
    float* out = (float*)d_out;

    char* ws = (char*)d_ws;
    u16* Xb  = (u16*)(ws);                       // 8 MB   X bf16 [4096][1024]
    u16* Wqb = (u16*)(ws + (size_t)( 8 << 20));  // 2 MB
    u16* Wkb = (u16*)(ws + (size_t)(10 << 20));  // 2 MB
    u16* Wvb = (u16*)(ws + (size_t)(12 << 20));  // 2 MB
    u16* Wob = (u16*)(ws + (size_t)(14 << 20));  // 2 MB
    u16* Qb  = (u16*)(ws + (size_t)(16 << 20));  // 8 MB   [h][s][64]
    u16* Kb  = (u16*)(ws + (size_t)(24 << 20));  // 8 MB   [h][s][64]
    u16* VTb = (u16*)(ws + (size_t)(32 << 20));  // 8 MB   [h][d][s]
    u16* AOb = (u16*)(ws + (size_t)(40 << 20));  // 8 MB   [s][1024]

    const int n4h = (S_LEN * HDIM) / 4;   // 1048576
    const int n4w = (HDIM * HDIM) / 4;    // 262144
    cvt_f32_bf16<<<n4h / 256, 256, 0, stream>>>(hidden, Xb, n4h);
    cvt_f32_bf16<<<n4w / 256, 256, 0, stream>>>(Wq, Wqb, n4w);
    cvt_f32_bf16<<<n4w / 256, 256, 0, stream>>>(Wk, Wkb, n4w);
    cvt_f32_bf16<<<n4w / 256, 256, 0, stream>>>(Wv, Wvb, n4w);
    cvt_f32_bf16<<<n4w / 256, 256, 0, stream>>>(Wo, Wob, n4w);

    dim3 gg(HDIM / 128, S_LEN / 128);  // (8, 32)
    gemm_bt<<<gg, 256, 0, stream>>>(Xb, Wqb, nullptr, Qb, cosT, sinT, 1);
    gemm_bt<<<gg, 256, 0, stream>>>(Xb, Wkb, nullptr, Kb, cosT, sinT, 2);
    gemm_bt<<<gg, 256, 0, stream>>>(Xb, Wvb, nullptr, VTb, nullptr, nullptr, 3);

    attn_fwd<<<dim3(S_LEN / 64, NHEADS), 256, 0, stream>>>(Qb, Kb, VTb, AOb);

    gemm_bt<<<gg, 256, 0, stream>>>(AOb, Wob, out, nullptr, nullptr, nullptr, 0);
}

// Round 3
// 253.034 us; speedup vs baseline: 1.2768x; 1.2492x over previous
//
#include <hip/hip_runtime.h>

#define S_LEN 4096
#define NHEADS 16
#define HD 64
#define HDIM 1024

typedef __attribute__((ext_vector_type(8))) __bf16 bf16x8;
typedef __attribute__((ext_vector_type(4))) float f32x4;
typedef unsigned short u16;

static __device__ __forceinline__ u16 f2bu(float f) {
    unsigned u = __builtin_bit_cast(unsigned, f);
    u += 0x7FFFu + ((u >> 16) & 1u);
    return (u16)(u >> 16);
}
static __device__ __forceinline__ u16 f2bu_trunc(float f) {
    return (u16)(__builtin_bit_cast(unsigned, f) >> 16);
}
static __device__ __forceinline__ float fexp2(float x) {
    return __builtin_amdgcn_exp2f(x);
}

// swizzled LDS fragment read: tile rows are 128B, XOR-swizzle ((row&7)<<4)
static __device__ __forceinline__ bf16x8 read_frag(const u16* lds, int row, int kbyte) {
    int c = kbyte ^ ((row & 7) << 4);
    return *reinterpret_cast<const bf16x8*>(reinterpret_cast<const char*>(lds) + row * 128 + c);
}

static __device__ __forceinline__ void stage_gll(const u16* __restrict__ src, u16* lds, unsigned ldsbyte) {
    __builtin_amdgcn_global_load_lds(
        (const __attribute__((address_space(1))) void*)src,
        (__attribute__((address_space(3))) void*)(reinterpret_cast<char*>(lds) + ldsbyte),
        16, 0, 0);
}

__global__ void cvt_f32_bf16(const float* __restrict__ src, u16* __restrict__ dst, int n4) {
    int i = blockIdx.x * blockDim.x + threadIdx.x;
    if (i < n4) {
        float4 v = reinterpret_cast<const float4*>(src)[i];
        ushort4 o;
        o.x = f2bu(v.x); o.y = f2bu(v.y); o.z = f2bu(v.z); o.w = f2bu(v.w);
        reinterpret_cast<ushort4*>(dst)[i] = o;
    }
}

// C[M,N] = A[M,K] @ W[N,K]^T,  M=4096 N=1024 K=1024, bf16 in, epilogue by mode:
// mode 0: fp32 out [s][1024]
// mode 1: RoPE + (0.125*log2e) scale, bf16 out [h][s][64]   (Q, exp2-domain)
// mode 2: RoPE, bf16 out [h][s][64]                         (K)
// mode 3: bf16 out transposed [h][d][s]                     (V^T)
__global__ __launch_bounds__(256) void gemm_bt(
    const u16* __restrict__ A, const u16* __restrict__ W,
    float* __restrict__ outF, u16* __restrict__ outB,
    const float* __restrict__ cosT, const float* __restrict__ sinT,
    int mode)
{
    __shared__ u16 At[128 * 64];
    __shared__ u16 Bt[128 * 64];
    const int tid = threadIdx.x;
    const int wid = tid >> 6, lane = tid & 63;
    const int wm = wid >> 1, wn = wid & 1;
    const int lj = lane >> 4, lc = lane & 15;
    const int m0 = blockIdx.y * 128, n0 = blockIdx.x * 128;

    f32x4 acc[4][4];
#pragma unroll
    for (int i = 0; i < 4; ++i)
#pragma unroll
        for (int j = 0; j < 4; ++j) acc[i][j] = 0.0f;

    for (int k0 = 0; k0 < HDIM; k0 += 64) {
        __syncthreads();
#pragma unroll
        for (int r = 0; r < 4; ++r) {
            int idx = (r << 8) + tid;
            int row = idx >> 3;              // 8 x 16B chunks per 128B row
            int c = (idx & 7) << 4;
            int csw = c ^ ((row & 7) << 4);  // inverse-swizzled source (same involution)
            unsigned lb = (unsigned)(idx & ~63) << 4;  // wave-uniform LDS base
            stage_gll(A + (size_t)(m0 + row) * HDIM + k0 + (csw >> 1), At, lb);
            stage_gll(W + (size_t)(n0 + row) * HDIM + k0 + (csw >> 1), Bt, lb);
        }
        __syncthreads();
#pragma unroll
        for (int kb = 0; kb < 2; ++kb) {
            int kbyte = (kb << 6) + (lj << 4);
            bf16x8 af[4], bfr[4];
#pragma unroll
            for (int mf = 0; mf < 4; ++mf) af[mf] = read_frag(At, (wm << 6) + (mf << 4) + lc, kbyte);
#pragma unroll
            for (int nf = 0; nf < 4; ++nf) bfr[nf] = read_frag(Bt, (wn << 6) + (nf << 4) + lc, kbyte);
#pragma unroll
            for (int mf = 0; mf < 4; ++mf)
#pragma unroll
                for (int nf = 0; nf < 4; ++nf)
                    acc[mf][nf] = __builtin_amdgcn_mfma_f32_16x16x32_bf16(af[mf], bfr[nf], acc[mf][nf], 0, 0, 0);
        }
    }

    const int mrow0 = m0 + (wm << 6);
    const int ncol0 = n0 + (wn << 6);
    if (mode == 0) {
#pragma unroll
        for (int mf = 0; mf < 4; ++mf)
#pragma unroll
            for (int nf = 0; nf < 4; ++nf)
#pragma unroll
                for (int j = 0; j < 4; ++j) {
                    int s = mrow0 + (mf << 4) + (lj << 2) + j;
                    int o = ncol0 + (nf << 4) + lc;
                    outF[(size_t)s * HDIM + o] = acc[mf][nf][j];
                }
    } else if (mode == 3) {
#pragma unroll
        for (int mf = 0; mf < 4; ++mf)
#pragma unroll
            for (int nf = 0; nf < 4; ++nf)
#pragma unroll
                for (int j = 0; j < 4; ++j) {
                    int s = mrow0 + (mf << 4) + (lj << 2) + j;
                    int o = ncol0 + (nf << 4) + lc;
                    outB[((size_t)(o >> 6) * HD + (o & 63)) * S_LEN + s] = f2bu(acc[mf][nf][j]);
                }
    } else {
        const float sc = (mode == 1) ? 0.18033688011112042f : 1.0f;  // 0.125*log2(e) for Q
#pragma unroll
        for (int mf = 0; mf < 4; ++mf) {
            float nv[4][4];
#pragma unroll
            for (int nf = 0; nf < 4; ++nf)
#pragma unroll
                for (int j = 0; j < 4; ++j) {
                    int s = mrow0 + (mf << 4) + (lj << 2) + j;
                    int o = ncol0 + (nf << 4) + lc;
                    int d = o & 63;
                    float x  = acc[mf][nf][j];
                    float xp = acc[mf][nf ^ 2][j];   // partner d +/- 32 lives 2 n-frags away
                    float cv = cosT[(size_t)s * HD + d];
                    float sv = sinT[(size_t)s * HD + d];
                    float rot = (d < 32) ? -xp : xp;
                    nv[nf][j] = (x * cv + rot * sv) * sc;
                }
#pragma unroll
            for (int nf = 0; nf < 4; ++nf)
#pragma unroll
                for (int j = 0; j < 4; ++j) {
                    int s = mrow0 + (mf << 4) + (lj << 2) + j;
                    int o = ncol0 + (nf << 4) + lc;
                    outB[((size_t)(o >> 6) * S_LEN + s) * HD + (o & 63)] = f2bu(nv[nf][j]);
                }
        }
    }
}

// Flash attention, causal, exp2-domain (Q pre-scaled by 0.125*log2e).
// Q,K: [h][s][64] bf16 (roped). VT: [h][d][s] bf16. Out: attn_out [s][h*64+d] bf16.
// Block = 4 waves x 32 q-rows = 128 q rows; KV tiles of 64, double-buffered prefetch.
// Grid = 512 linear blocks; lid -> (h, qt) XCD-aware + heavy/light pairing.
__global__ __launch_bounds__(256) void attn_fwd(
    const u16* __restrict__ Q, const u16* __restrict__ K,
    const u16* __restrict__ VT, u16* __restrict__ AO)
{
    __shared__ u16 Kt[2][64 * 64];   // [buf][kv][d], swizzled
    __shared__ u16 Vt[2][64 * 64];   // [buf][d][kv], swizzled
    __shared__ u16 Pt[4][32 * 64];   // per-wave P (32 q rows x 64 kv), swizzled

    const int tid = threadIdx.x;
    const int wid = tid >> 6, lane = tid & 63;
    const int lj = lane >> 4, lc = lane & 15;

    // lid -> (h, qt): XCD gets 2 consecutive heads (K/V of 2 heads ~ 2MB fits XCD L2);
    // qt order pairs heavy (31-j) for head0 with light (j) for head1 -> balanced CUs.
    const int lid = blockIdx.x;
    const int kk = lid >> 3;                       // 0..63
    const int h  = ((lid & 7) << 1) | (kk >> 5);
    const int qs = kk & 31;
    const int qt = (kk >> 5) ? qs : 31 - qs;
    const int qbase = qt * 128 + wid * 32;         // this wave's 32 q-rows

    const u16* Qh  = Q  + (size_t)h * S_LEN * HD;
    const u16* Kh  = K  + (size_t)h * S_LEN * HD;
    const u16* VTh = VT + (size_t)h * HD * S_LEN;
    u16* Pw = Pt[wid];

    bf16x8 qA[2][2];
#pragma unroll
    for (int qf = 0; qf < 2; ++qf)
#pragma unroll
        for (int kb = 0; kb < 2; ++kb)
            qA[qf][kb] = *reinterpret_cast<const bf16x8*>(
                Qh + (size_t)(qbase + (qf << 4) + lc) * HD + (kb << 5) + (lj << 3));

    f32x4 accO[2][4];
    float m_run[2][4], l_part[2][4];
#pragma unroll
    for (int qf = 0; qf < 2; ++qf) {
#pragma unroll
        for (int df = 0; df < 4; ++df) accO[qf][df] = 0.0f;
#pragma unroll
        for (int j = 0; j < 4; ++j) { m_run[qf][j] = -1e30f; l_part[qf][j] = 0.0f; }
    }

    const int nt = 2 * qt + 2;   // causal: kv tiles of 64 needed for 128 q rows

    // prologue: stage tile 0 into buffer 0
#pragma unroll
    for (int r = 0; r < 2; ++r) {
        int idx = (r << 8) + tid;
        int row = idx >> 3;
        int c = (idx & 7) << 4;
        int csw = c ^ ((row & 7) << 4);
        unsigned lb = (unsigned)(idx & ~63) << 4;
        stage_gll(Kh + (size_t)row * HD + (csw >> 1), Kt[0], lb);
        stage_gll(VTh + (size_t)row * S_LEN + (csw >> 1), Vt[0], lb);
    }
    __syncthreads();

    for (int t = 0; t < nt; ++t) {
        const int cur = t & 1;
        // prefetch next tile into the other buffer (overlaps with compute below)
        if (t + 1 < nt) {
            const int kvn = (t + 1) << 6;
#pragma unroll
            for (int r = 0; r < 2; ++r) {
                int idx = (r << 8) + tid;
                int row = idx >> 3;
                int c = (idx & 7) << 4;
                int csw = c ^ ((row & 7) << 4);
                unsigned lb = (unsigned)(idx & ~63) << 4;
                stage_gll(Kh + (size_t)(kvn + row) * HD + (csw >> 1), Kt[cur ^ 1], lb);
                stage_gll(VTh + (size_t)row * S_LEN + kvn + (csw >> 1), Vt[cur ^ 1], lb);
            }
        }

        const int kv0 = t << 6;
        if (kv0 <= qbase + 31) {
            // QK^T : 32 q-rows x 64 kv
            f32x4 sf[2][4];
#pragma unroll
            for (int qf = 0; qf < 2; ++qf)
#pragma unroll
                for (int nf = 0; nf < 4; ++nf) sf[qf][nf] = 0.0f;
            __builtin_amdgcn_s_setprio(1);
#pragma unroll
            for (int kb = 0; kb < 2; ++kb) {
                int kbyte = (kb << 6) + (lj << 4);
#pragma unroll
                for (int nf = 0; nf < 4; ++nf) {
                    bf16x8 kf = read_frag(Kt[cur], (nf << 4) + lc, kbyte);
#pragma unroll
                    for (int qf = 0; qf < 2; ++qf)
                        sf[qf][nf] = __builtin_amdgcn_mfma_f32_16x16x32_bf16(qA[qf][kb], kf, sf[qf][nf], 0, 0, 0);
                }
            }
            __builtin_amdgcn_s_setprio(0);

            if (kv0 + 63 > qbase) {  // diagonal region: causal mask
#pragma unroll
                for (int qf = 0; qf < 2; ++qf)
#pragma unroll
                    for (int nf = 0; nf < 4; ++nf)
#pragma unroll
                        for (int j = 0; j < 4; ++j) {
                            int kvg = kv0 + (nf << 4) + lc;
                            int qg  = qbase + (qf << 4) + (lj << 2) + j;
                            if (kvg > qg) sf[qf][nf][j] = -1e30f;
                        }
            }

            // online softmax (exp2 domain), defer-max, per-lane partial l
#pragma unroll
            for (int qf = 0; qf < 2; ++qf) {
                float mx[4];
#pragma unroll
                for (int j = 0; j < 4; ++j)
                    mx[j] = fmaxf(fmaxf(sf[qf][0][j], sf[qf][1][j]), fmaxf(sf[qf][2][j], sf[qf][3][j]));
#pragma unroll
                for (int off = 1; off < 16; off <<= 1)
#pragma unroll
                    for (int j = 0; j < 4; ++j) mx[j] = fmaxf(mx[j], __shfl_xor(mx[j], off));

                bool grow = false;
#pragma unroll
                for (int j = 0; j < 4; ++j) grow = grow || (mx[j] > m_run[qf][j] + 8.0f);
                if (__any(grow)) {
#pragma unroll
                    for (int j = 0; j < 4; ++j) {
                        float mn = fmaxf(m_run[qf][j], mx[j]);
                        float scl = fexp2(m_run[qf][j] - mn);
                        m_run[qf][j] = mn;
                        l_part[qf][j] *= scl;
#pragma unroll
                        for (int df = 0; df < 4; ++df) accO[qf][df][j] *= scl;
                    }
                }

#pragma unroll
                for (int nf = 0; nf < 4; ++nf)
#pragma unroll
                    for (int j = 0; j < 4; ++j) {
                        float p = fexp2(sf[qf][nf][j] - m_run[qf][j]);
                        l_part[qf][j] += p;
                        int prow = (qf << 4) + (lj << 2) + j;
                        int cb = (((nf << 4) + lc) << 1) ^ ((prow & 7) << 4);
                        Pw[prow * 64 + (cb >> 1)] = f2bu_trunc(p);
                    }
            }

            // PV
            __builtin_amdgcn_s_setprio(1);
#pragma unroll
            for (int kb = 0; kb < 2; ++kb) {
                int kbyte = (kb << 6) + (lj << 4);
                bf16x8 pf[2];
#pragma unroll
                for (int qf = 0; qf < 2; ++qf) pf[qf] = read_frag(Pw, (qf << 4) + lc, kbyte);
#pragma unroll
                for (int df = 0; df < 4; ++df) {
                    bf16x8 vf = read_frag(Vt[cur], (df << 4) + lc, kbyte);
#pragma unroll
                    for (int qf = 0; qf < 2; ++qf)
                        accO[qf][df] = __builtin_amdgcn_mfma_f32_16x16x32_bf16(pf[qf], vf, accO[qf][df], 0, 0, 0);
                }
            }
            __builtin_amdgcn_s_setprio(0);
        }
        __syncthreads();   // drains prefetch vmcnt + syncs LDS buffer swap
    }

    // epilogue: finish the deferred cross-lane l reduction, normalize, store
#pragma unroll
    for (int qf = 0; qf < 2; ++qf) {
#pragma unroll
        for (int off = 1; off < 16; off <<= 1)
#pragma unroll
            for (int j = 0; j < 4; ++j) l_part[qf][j] += __shfl_xor(l_part[qf][j], off);
#pragma unroll
        for (int df = 0; df < 4; ++df)
#pragma unroll
            for (int j = 0; j < 4; ++j) {
                int s = qbase + (qf << 4) + (lj << 2) + j;
                int d = (df << 4) + lc;
                float v = accO[qf][df][j] / l_part[qf][j];
                AO[(size_t)s * HDIM + h * HD + d] = f2bu(v);
            }
    }
}

extern "C" void kernel_launch(void* const* d_in, const int* in_sizes, int n_in,
                              void* d_out, int out_size, void* d_ws, size_t ws_size,
                              hipStream_t stream) {
    const float* hidden = (const float*)d_in[0];
    const float* cosT   = (const float*)d_in[1];
    const float* sinT   = (const float*)d_in[2];
    // d_in[3] = attention_mask (fixed causal tril) — implemented directly
    const float* Wq = (const float*)d_in[4];
    const float* Wk = (const float*)d_in[5];
    const float* Wv = (const float*)d_in[6];
    const float* Wo = (const float*)d_in[7];
    float* out = (float*)d_out;

    char* ws = (char*)d_ws;
    u16* Xb  = (u16*)(ws);                       // 8 MB   X bf16 [4096][1024]
    u16* Wqb = (u16*)(ws + (size_t)( 8 << 20));  // 2 MB
    u16* Wkb = (u16*)(ws + (size_t)(10 << 20));  // 2 MB
    u16* Wvb = (u16*)(ws + (size_t)(12 << 20));  // 2 MB
    u16* Wob = (u16*)(ws + (size_t)(14 << 20));  // 2 MB
    u16* Qb  = (u16*)(ws + (size_t)(16 << 20));  // 8 MB   [h][s][64]
    u16* Kb  = (u16*)(ws + (size_t)(24 << 20));  // 8 MB   [h][s][64]
    u16* VTb = (u16*)(ws + (size_t)(32 << 20));  // 8 MB   [h][d][s]
    u16* AOb = (u16*)(ws + (size_t)(40 << 20));  // 8 MB   [s][1024]

    const int n4h = (S_LEN * HDIM) / 4;   // 1048576
    const int n4w = (HDIM * HDIM) / 4;    // 262144
    cvt_f32_bf16<<<n4h / 256, 256, 0, stream>>>(hidden, Xb, n4h);
    cvt_f32_bf16<<<n4w / 256, 256, 0, stream>>>(Wq, Wqb, n4w);
    cvt_f32_bf16<<<n4w / 256, 256, 0, stream>>>(Wk, Wkb, n4w);
    cvt_f32_bf16<<<n4w / 256, 256, 0, stream>>>(Wv, Wvb, n4w);
    cvt_f32_bf16<<<n4w / 256, 256, 0, stream>>>(Wo, Wob, n4w);

    dim3 gg(HDIM / 128, S_LEN / 128);  // (8, 32)
    gemm_bt<<<gg, 256, 0, stream>>>(Xb, Wqb, nullptr, Qb, cosT, sinT, 1);
    gemm_bt<<<gg, 256, 0, stream>>>(Xb, Wkb, nullptr, Kb, cosT, sinT, 2);
    gemm_bt<<<gg, 256, 0, stream>>>(Xb, Wvb, nullptr, VTb, nullptr, nullptr, 3);

    attn_fwd<<<dim3(512), 256, 0, stream>>>(Qb, Kb, VTb, AOb);

    gemm_bt<<<gg, 256, 0, stream>>>(AOb, Wob, out, nullptr, nullptr, nullptr, 0);
}

// Round 4
// 194.160 us; speedup vs baseline: 1.6640x; 1.3032x over previous
//
#include <hip/hip_runtime.h>

#define S_LEN 4096
#define NHEADS 16
#define HD 64
#define HDIM 1024

typedef __attribute__((ext_vector_type(8))) __bf16 bf16x8;
typedef __attribute__((ext_vector_type(4))) float f32x4;
typedef __attribute__((ext_vector_type(4))) int i32x4;
typedef unsigned short u16;

static __device__ __forceinline__ u16 f2bu(float f) {
    unsigned u = __builtin_bit_cast(unsigned, f);
    u += 0x7FFFu + ((u >> 16) & 1u);
    return (u16)(u >> 16);
}
static __device__ __forceinline__ int pack_trunc(float lo, float hi) {
    return (int)((__builtin_bit_cast(unsigned, hi) & 0xFFFF0000u) |
                 (__builtin_bit_cast(unsigned, lo) >> 16));
}
static __device__ __forceinline__ float fexp2(float x) {
    return __builtin_amdgcn_exp2f(x);
}

// swizzled LDS fragment read: tile rows are 128B, XOR-swizzle ((row&7)<<4)
static __device__ __forceinline__ bf16x8 read_frag(const u16* lds, int row, int kbyte) {
    int c = kbyte ^ ((row & 7) << 4);
    return *reinterpret_cast<const bf16x8*>(reinterpret_cast<const char*>(lds) + row * 128 + c);
}

static __device__ __forceinline__ void stage_gll(const u16* __restrict__ src, u16* lds, unsigned ldsbyte) {
    __builtin_amdgcn_global_load_lds(
        (const __attribute__((address_space(1))) void*)src,
        (__attribute__((address_space(3))) void*)(reinterpret_cast<char*>(lds) + ldsbyte),
        16, 0, 0);
}

// one fused convert: X (1M float4) then Wq,Wk,Wv,Wo (256K float4 each)
__global__ __launch_bounds__(256) void cvt_all(
    const float* __restrict__ X, const float* __restrict__ Wq, const float* __restrict__ Wk,
    const float* __restrict__ Wv, const float* __restrict__ Wo,
    u16* __restrict__ Xb, u16* __restrict__ Wqb, u16* __restrict__ Wkb,
    u16* __restrict__ Wvb, u16* __restrict__ Wob)
{
    int i = blockIdx.x * 256 + threadIdx.x;
    const float* src; u16* dst; int off;
    if (i < (1 << 20)) { src = X; dst = Xb; off = i; }
    else {
        int j = i - (1 << 20);
        int w = j >> 18; off = j & 0x3FFFF;
        src = (w == 0) ? Wq : (w == 1) ? Wk : (w == 2) ? Wv : Wo;
        dst = (w == 0) ? Wqb : (w == 1) ? Wkb : (w == 2) ? Wvb : Wob;
    }
    float4 v = reinterpret_cast<const float4*>(src)[off];
    ushort4 o;
    o.x = f2bu(v.x); o.y = f2bu(v.y); o.z = f2bu(v.z); o.w = f2bu(v.w);
    reinterpret_cast<ushort4*>(dst)[off] = o;
}

// Fused Q/K/V projections: z=0 Q (RoPE + 0.125*log2e, [h][s][64]),
// z=1 K (RoPE, [h][s][64]), z=2 V (transposed [h][d][s]).
__global__ __launch_bounds__(256) void qkv_gemm(
    const u16* __restrict__ A,
    const u16* __restrict__ Wq, const u16* __restrict__ Wk, const u16* __restrict__ Wv,
    u16* __restrict__ Qb, u16* __restrict__ Kb, u16* __restrict__ VTb,
    const float* __restrict__ cosT, const float* __restrict__ sinT)
{
    __shared__ u16 At[128 * 64];
    __shared__ u16 Bt[128 * 64];
    const int z = blockIdx.z;
    const u16* W = (z == 0) ? Wq : (z == 1) ? Wk : Wv;
    const int tid = threadIdx.x;
    const int wid = tid >> 6, lane = tid & 63;
    const int wm = wid >> 1, wn = wid & 1;
    const int lj = lane >> 4, lc = lane & 15;
    const int m0 = blockIdx.y * 128, n0 = blockIdx.x * 128;

    f32x4 acc[4][4];
#pragma unroll
    for (int i = 0; i < 4; ++i)
#pragma unroll
        for (int j = 0; j < 4; ++j) acc[i][j] = 0.0f;

    for (int k0 = 0; k0 < HDIM; k0 += 64) {
        __syncthreads();
#pragma unroll
        for (int r = 0; r < 4; ++r) {
            int idx = (r << 8) + tid;
            int row = idx >> 3;
            int c = (idx & 7) << 4;
            int csw = c ^ ((row & 7) << 4);
            unsigned lb = (unsigned)(idx & ~63) << 4;
            stage_gll(A + (size_t)(m0 + row) * HDIM + k0 + (csw >> 1), At, lb);
            stage_gll(W + (size_t)(n0 + row) * HDIM + k0 + (csw >> 1), Bt, lb);
        }
        __syncthreads();
#pragma unroll
        for (int kb = 0; kb < 2; ++kb) {
            int kbyte = (kb << 6) + (lj << 4);
            bf16x8 af[4], bfr[4];
#pragma unroll
            for (int mf = 0; mf < 4; ++mf) af[mf] = read_frag(At, (wm << 6) + (mf << 4) + lc, kbyte);
#pragma unroll
            for (int nf = 0; nf < 4; ++nf) bfr[nf] = read_frag(Bt, (wn << 6) + (nf << 4) + lc, kbyte);
#pragma unroll
            for (int mf = 0; mf < 4; ++mf)
#pragma unroll
                for (int nf = 0; nf < 4; ++nf)
                    acc[mf][nf] = __builtin_amdgcn_mfma_f32_16x16x32_bf16(af[mf], bfr[nf], acc[mf][nf], 0, 0, 0);
        }
    }

    const int mrow0 = m0 + (wm << 6);
    const int ncol0 = n0 + (wn << 6);
    if (z == 2) {
#pragma unroll
        for (int mf = 0; mf < 4; ++mf)
#pragma unroll
            for (int nf = 0; nf < 4; ++nf)
#pragma unroll
                for (int j = 0; j < 4; ++j) {
                    int s = mrow0 + (mf << 4) + (lj << 2) + j;
                    int o = ncol0 + (nf << 4) + lc;
                    VTb[((size_t)(o >> 6) * HD + (o & 63)) * S_LEN + s] = f2bu(acc[mf][nf][j]);
                }
    } else {
        u16* outB = (z == 0) ? Qb : Kb;
        const float sc = (z == 0) ? 0.18033688011112042f : 1.0f;  // 0.125*log2(e) for Q
#pragma unroll
        for (int mf = 0; mf < 4; ++mf) {
            float nv[4][4];
#pragma unroll
            for (int nf = 0; nf < 4; ++nf)
#pragma unroll
                for (int j = 0; j < 4; ++j) {
                    int s = mrow0 + (mf << 4) + (lj << 2) + j;
                    int o = ncol0 + (nf << 4) + lc;
                    int d = o & 63;
                    float x  = acc[mf][nf][j];
                    float xp = acc[mf][nf ^ 2][j];
                    float cv = cosT[(size_t)s * HD + d];
                    float sv = sinT[(size_t)s * HD + d];
                    float rot = (d < 32) ? -xp : xp;
                    nv[nf][j] = (x * cv + rot * sv) * sc;
                }
#pragma unroll
            for (int nf = 0; nf < 4; ++nf)
#pragma unroll
                for (int j = 0; j < 4; ++j) {
                    int s = mrow0 + (mf << 4) + (lj << 2) + j;
                    int o = ncol0 + (nf << 4) + lc;
                    outB[((size_t)(o >> 6) * S_LEN + s) * HD + (o & 63)] = f2bu(nv[nf][j]);
                }
        }
    }
}

// Output projection: out[s][o] = AO[s][:] @ Wo[o][:]^T, fp32 out
__global__ __launch_bounds__(256) void wo_gemm(
    const u16* __restrict__ A, const u16* __restrict__ W, float* __restrict__ outF)
{
    __shared__ u16 At[128 * 64];
    __shared__ u16 Bt[128 * 64];
    const int tid = threadIdx.x;
    const int wid = tid >> 6, lane = tid & 63;
    const int wm = wid >> 1, wn = wid & 1;
    const int lj = lane >> 4, lc = lane & 15;
    const int m0 = blockIdx.y * 128, n0 = blockIdx.x * 128;

    f32x4 acc[4][4];
#pragma unroll
    for (int i = 0; i < 4; ++i)
#pragma unroll
        for (int j = 0; j < 4; ++j) acc[i][j] = 0.0f;

    for (int k0 = 0; k0 < HDIM; k0 += 64) {
        __syncthreads();
#pragma unroll
        for (int r = 0; r < 4; ++r) {
            int idx = (r << 8) + tid;
            int row = idx >> 3;
            int c = (idx & 7) << 4;
            int csw = c ^ ((row & 7) << 4);
            unsigned lb = (unsigned)(idx & ~63) << 4;
            stage_gll(A + (size_t)(m0 + row) * HDIM + k0 + (csw >> 1), At, lb);
            stage_gll(W + (size_t)(n0 + row) * HDIM + k0 + (csw >> 1), Bt, lb);
        }
        __syncthreads();
#pragma unroll
        for (int kb = 0; kb < 2; ++kb) {
            int kbyte = (kb << 6) + (lj << 4);
            bf16x8 af[4], bfr[4];
#pragma unroll
            for (int mf = 0; mf < 4; ++mf) af[mf] = read_frag(At, (wm << 6) + (mf << 4) + lc, kbyte);
#pragma unroll
            for (int nf = 0; nf < 4; ++nf) bfr[nf] = read_frag(Bt, (wn << 6) + (nf << 4) + lc, kbyte);
#pragma unroll
            for (int mf = 0; mf < 4; ++mf)
#pragma unroll
                for (int nf = 0; nf < 4; ++nf)
                    acc[mf][nf] = __builtin_amdgcn_mfma_f32_16x16x32_bf16(af[mf], bfr[nf], acc[mf][nf], 0, 0, 0);
        }
    }

    const int mrow0 = m0 + (wm << 6);
    const int ncol0 = n0 + (wn << 6);
#pragma unroll
    for (int mf = 0; mf < 4; ++mf)
#pragma unroll
        for (int nf = 0; nf < 4; ++nf)
#pragma unroll
            for (int j = 0; j < 4; ++j) {
                int s = mrow0 + (mf << 4) + (lj << 2) + j;
                int o = ncol0 + (nf << 4) + lc;
                outF[(size_t)s * HDIM + o] = acc[mf][nf][j];
            }
}

// Flash attention, causal, exp2-domain (Q pre-scaled by 0.125*log2e).
// Swapped QK^T: sf = mfma(K_frag, Q_frag) -> S^T, col=lane&15 = q-row, so each lane
// owns 16 P values of one q-row; softmax is in-lane + 2 shuffles; P never hits LDS.
// Block = 4 waves x 16 q-rows = 64 q rows; KV tiles 64, double-buffered prefetch.
// Grid 1024; mapping gives each CU 4 blocks with constant total work (130 steps).
__global__ __launch_bounds__(256, 4) void attn_fwd(
    const u16* __restrict__ Q, const u16* __restrict__ K,
    const u16* __restrict__ VT, u16* __restrict__ AO)
{
    __shared__ u16 Kt[2][64 * 64];   // [buf][kv][d], swizzled
    __shared__ u16 Vt[2][64 * 64];   // [buf][d][kv], swizzled

    const int tid = threadIdx.x;
    const int wid = tid >> 6, lane = tid & 63;
    const int lj = lane >> 4, lc = lane & 15;

    // lid -> (h, qt): xcd = lid&7 serves heads {2x,2x+1} (2MB K/V fits XCD L2).
    // Round a = (lid>>3)>>5: qt = (a&1) ? b : 63-b  ->  CU round-robin residues give
    // each CU qt {63-b, b, 63-b, b}: constant 130 KV-steps per CU, heavy-first.
    const int lid = blockIdx.x;
    const int x = lid & 7, g = lid >> 3;
    const int a = g >> 5, b = g & 31;
    const int h = (x << 1) | (a >> 1);
    const int qt = (a & 1) ? b : 63 - b;
    const int qbase = qt * 64 + wid * 16;    // this wave's 16 q-rows

    const u16* Qh  = Q  + (size_t)h * S_LEN * HD;
    const u16* Kh  = K  + (size_t)h * S_LEN * HD;
    const u16* VTh = VT + (size_t)h * HD * S_LEN;

    bf16x8 qB[2];   // B-operand: lane holds Q[q=lc][k-slice lj]
#pragma unroll
    for (int kb = 0; kb < 2; ++kb)
        qB[kb] = *reinterpret_cast<const bf16x8*>(
            Qh + (size_t)(qbase + lc) * HD + (kb << 5) + (lj << 3));

    f32x4 accO[4];
    float m_run = -1e30f, l_part = 0.0f;
#pragma unroll
    for (int df = 0; df < 4; ++df) accO[df] = 0.0f;

    const int nt = qt + 1;

    // prologue: stage tile 0 into buffer 0
#pragma unroll
    for (int r = 0; r < 2; ++r) {
        int idx = (r << 8) + tid;
        int row = idx >> 3;
        int c = (idx & 7) << 4;
        int csw = c ^ ((row & 7) << 4);
        unsigned lb = (unsigned)(idx & ~63) << 4;
        stage_gll(Kh + (size_t)row * HD + (csw >> 1), Kt[0], lb);
        stage_gll(VTh + (size_t)row * S_LEN + (csw >> 1), Vt[0], lb);
    }
    __syncthreads();

    for (int t = 0; t < nt; ++t) {
        const int cur = t & 1;
        if (t + 1 < nt) {
            const int kvn = (t + 1) << 6;
#pragma unroll
            for (int r = 0; r < 2; ++r) {
                int idx = (r << 8) + tid;
                int row = idx >> 3;
                int c = (idx & 7) << 4;
                int csw = c ^ ((row & 7) << 4);
                unsigned lb = (unsigned)(idx & ~63) << 4;
                stage_gll(Kh + (size_t)(kvn + row) * HD + (csw >> 1), Kt[cur ^ 1], lb);
                stage_gll(VTh + (size_t)row * S_LEN + kvn + (csw >> 1), Vt[cur ^ 1], lb);
            }
        }

        const int kv0 = t << 6;
        if (kv0 <= qbase + 15) {
            // QK^T swapped: sf[nf][j] = S[kv = kv0+16nf+4lj+j][q = qbase+lc]
            f32x4 sf[4];
#pragma unroll
            for (int nf = 0; nf < 4; ++nf) sf[nf] = 0.0f;
            __builtin_amdgcn_s_setprio(1);
#pragma unroll
            for (int kb = 0; kb < 2; ++kb) {
                int kbyte = (kb << 6) + (lj << 4);
#pragma unroll
                for (int nf = 0; nf < 4; ++nf) {
                    bf16x8 kf = read_frag(Kt[cur], (nf << 4) + lc, kbyte);
                    sf[nf] = __builtin_amdgcn_mfma_f32_16x16x32_bf16(kf, qB[kb], sf[nf], 0, 0, 0);
                }
            }
            __builtin_amdgcn_s_setprio(0);

            if (kv0 + 63 > qbase) {  // diagonal region: causal mask (q-row is lc!)
                int qg = qbase + lc;
#pragma unroll
                for (int nf = 0; nf < 4; ++nf)
#pragma unroll
                    for (int j = 0; j < 4; ++j) {
                        int kvg = kv0 + (nf << 4) + (lj << 2) + j;
                        if (kvg > qg) sf[nf][j] = -1e30f;
                    }
            }

            // in-lane row max (16 values) + 2 shuffles across the 4 lanes sharing lc
            float mx01 = fmaxf(fmaxf(sf[0][0], sf[0][1]), fmaxf(sf[0][2], sf[0][3]));
            float mx1  = fmaxf(fmaxf(sf[1][0], sf[1][1]), fmaxf(sf[1][2], sf[1][3]));
            float mx2  = fmaxf(fmaxf(sf[2][0], sf[2][1]), fmaxf(sf[2][2], sf[2][3]));
            float mx3  = fmaxf(fmaxf(sf[3][0], sf[3][1]), fmaxf(sf[3][2], sf[3][3]));
            float mx = fmaxf(fmaxf(mx01, mx1), fmaxf(mx2, mx3));
            mx = fmaxf(mx, __shfl_xor(mx, 16));
            mx = fmaxf(mx, __shfl_xor(mx, 32));

            if (__any(mx > m_run + 8.0f)) {   // defer-max rescale
                float mn = fmaxf(m_run, mx);
                float scl = fexp2(m_run - mn);
                m_run = mn;
                l_part *= scl;
                float sc4[4];
#pragma unroll
                for (int j = 0; j < 4; ++j) sc4[j] = __shfl(scl, (lj << 2) + j);
#pragma unroll
                for (int df = 0; df < 4; ++df)
#pragma unroll
                    for (int j = 0; j < 4; ++j) accO[df][j] *= sc4[j];
            }

            // P = exp2(S - m), per-lane partial l, pack pairs to bf16 u32s
            int pk[4][2];
#pragma unroll
            for (int nf = 0; nf < 4; ++nf) {
                float p0 = fexp2(sf[nf][0] - m_run);
                float p1 = fexp2(sf[nf][1] - m_run);
                float p2 = fexp2(sf[nf][2] - m_run);
                float p3 = fexp2(sf[nf][3] - m_run);
                l_part += (p0 + p1) + (p2 + p3);
                pk[nf][0] = pack_trunc(p0, p1);
                pk[nf][1] = pack_trunc(p2, p3);
            }

            // gather PV A-fragments: slot s pulls pair (s&1) of nf=2kb+(lj>>1)
            // from lane lc + 16*((2lj+(s>>1))&3)
            bf16x8 pf[2];
#pragma unroll
            for (int kb = 0; kb < 2; ++kb) {
                i32x4 u;
#pragma unroll
                for (int s = 0; s < 4; ++s) {
                    int srcl = lc + (((2 * lj + (s >> 1)) & 3) << 4);
                    int v0 = __shfl(pk[2 * kb][s & 1], srcl);
                    int v1 = __shfl(pk[2 * kb + 1][s & 1], srcl);
                    u[s] = (lj & 2) ? v1 : v0;
                }
                pf[kb] = __builtin_bit_cast(bf16x8, u);
            }

            // PV
            __builtin_amdgcn_s_setprio(1);
#pragma unroll
            for (int kb = 0; kb < 2; ++kb) {
                int kbyte = (kb << 6) + (lj << 4);
#pragma unroll
                for (int df = 0; df < 4; ++df) {
                    bf16x8 vf = read_frag(Vt[cur], (df << 4) + lc, kbyte);
                    accO[df] = __builtin_amdgcn_mfma_f32_16x16x32_bf16(pf[kb], vf, accO[df], 0, 0, 0);
                }
            }
            __builtin_amdgcn_s_setprio(0);
        }
        __syncthreads();
    }

    // epilogue: finish l reduction (4 lanes per q-row), normalize, store
    l_part += __shfl_xor(l_part, 16);
    l_part += __shfl_xor(l_part, 32);
    float lr[4];
#pragma unroll
    for (int j = 0; j < 4; ++j) lr[j] = __shfl(l_part, (lj << 2) + j);
#pragma unroll
    for (int df = 0; df < 4; ++df)
#pragma unroll
        for (int j = 0; j < 4; ++j) {
            int s = qbase + (lj << 2) + j;
            int d = (df << 4) + lc;
            AO[(size_t)s * HDIM + h * HD + d] = f2bu(accO[df][j] / lr[j]);
        }
}

extern "C" void kernel_launch(void* const* d_in, const int* in_sizes, int n_in,
                              void* d_out, int out_size, void* d_ws, size_t ws_size,
                              hipStream_t stream) {
    const float* hidden = (const float*)d_in[0];
    const float* cosT   = (const float*)d_in[1];
    const float* sinT   = (const float*)d_in[2];
    // d_in[3] = attention_mask (fixed causal tril) — implemented directly
    const float* Wq = (const float*)d_in[4];
    const float* Wk = (const float*)d_in[5];
    const float* Wv = (const float*)d_in[6];
    const float* Wo = (const float*)d_in[7];
    float* out = (float*)d_out;

    char* ws = (char*)d_ws;
    u16* Xb  = (u16*)(ws);                       // 8 MB   X bf16 [4096][1024]
    u16* Wqb = (u16*)(ws + (size_t)( 8 << 20));  // 2 MB
    u16* Wkb = (u16*)(ws + (size_t)(10 << 20));  // 2 MB
    u16* Wvb = (u16*)(ws + (size_t)(12 << 20));  // 2 MB
    u16* Wob = (u16*)(ws + (size_t)(14 << 20));  // 2 MB
    u16* Qb  = (u16*)(ws + (size_t)(16 << 20));  // 8 MB   [h][s][64]
    u16* Kb  = (u16*)(ws + (size_t)(24 << 20));  // 8 MB   [h][s][64]
    u16* VTb = (u16*)(ws + (size_t)(32 << 20));  // 8 MB   [h][d][s]
    u16* AOb = (u16*)(ws + (size_t)(40 << 20));  // 8 MB   [s][1024]

    // fused converts: 1M (X) + 4*256K (W) float4s = 2M items
    cvt_all<<<8192, 256, 0, stream>>>(hidden, Wq, Wk, Wv, Wo, Xb, Wqb, Wkb, Wvb, Wob);

    qkv_gemm<<<dim3(HDIM / 128, S_LEN / 128, 3), 256, 0, stream>>>(
        Xb, Wqb, Wkb, Wvb, Qb, Kb, VTb, cosT, sinT);

    attn_fwd<<<dim3(1024), 256, 0, stream>>>(Qb, Kb, VTb, AOb);

    wo_gemm<<<dim3(HDIM / 128, S_LEN / 128), 256, 0, stream>>>(AOb, Wob, out);
}